// Round 1
// baseline (320.231 us; speedup 1.0000x reference)
//
#include <hip/hip_runtime.h>

// Problem constants (from reference): S=56, B=5, C=20, N=128
constexpr int S_   = 56;
constexpr int B_   = 5;
constexpr int C_   = 20;
constexpr int N_   = 128;
constexpr int CELLS = N_ * S_ * S_;   // 401408
constexpr int PSTR  = B_ * (C_ + 5);  // 125 floats per cell (predicts)
constexpr int TSTR  = C_ + 5;         // 25 floats per cell (targets)

constexpr int TPB  = 256;             // 4 waves/block, zero LDS
constexpr int NBLK = CELLS / TPB;     // 1568, exact

constexpr int NBUCKET       = 64;
constexpr int BUCKET_STRIDE = 32;     // floats -> 128 B apart, no line sharing

// One cell per thread. No LDS staging: each cell's 500 B is contiguous and
// consumed by exactly one thread, so L1/L2 provide the locality; zero LDS +
// ~90 VGPR gives ~16-20 waves/CU (vs 4 for the full-staging version), which
// is what actually hides HBM latency for this memory-bound op.
__global__ __launch_bounds__(TPB, 4) void yolo_loss_kernel(
    const float* __restrict__ pred,
    const float* __restrict__ targ,
    const float* __restrict__ anch,   // [B,2]
    float* __restrict__ buckets)      // [NBUCKET * BUCKET_STRIDE] in d_ws
{
    const int cell = blockIdx.x * TPB + threadIdx.x;
    const float* __restrict__ pc = pred + (size_t)cell * PSTR;
    const float* __restrict__ tp = targ + (size_t)cell * TSTR;

    // ---- targets: 25 floats, unrolled -> merged dwordx4/x2 loads ----
    float t[TSTR];
    #pragma unroll
    for (int k = 0; k < TSTR; ++k) t[k] = tp[k];

    // ---- pred geometry: p[b*25 + 20..24] for all 5 boxes (obj,cx,cy,w,h) ----
    float pobj[B_], prx[B_], pry[B_], prw[B_], prh[B_];
    #pragma unroll
    for (int b = 0; b < B_; ++b) {
        pobj[b] = pc[b * TSTR + C_];
        prx[b]  = pc[b * TSTR + C_ + 1];
        pry[b]  = pc[b * TSTR + C_ + 2];
        prw[b]  = pc[b * TSTR + C_ + 3];
        prh[b]  = pc[b * TSTR + C_ + 4];
    }

    // anchors: 10 uniform floats (scalar-load / L1 broadcast)
    float aw[B_], ah[B_];
    #pragma unroll
    for (int b = 0; b < B_; ++b) { aw[b] = anch[2 * b]; ah[b] = anch[2 * b + 1]; }

    const float tcx = t[C_ + 1], tcy = t[C_ + 2];
    const float tw  = t[C_ + 3], th  = t[C_ + 4];
    const float tx0 = tcx - 0.5f * tw, ty0 = tcy - 0.5f * th;
    const float tx1 = tcx + 0.5f * tw, ty1 = tcy + 0.5f * th;
    const float area_t = tw * th;

    float best_iou = -1.f;
    int   best_b = 0;
    float bcx = 0.f, bcy = 0.f, bw = 0.f, bh = 0.f, bobj = 0.f;

    #pragma unroll
    for (int b = 0; b < B_; ++b) {
        const float cx = __builtin_amdgcn_rcpf(1.f + __expf(-prx[b])); // sigmoid
        const float cy = __builtin_amdgcn_rcpf(1.f + __expf(-pry[b]));
        const float w  = __expf(prw[b]) * aw[b];
        const float h  = __expf(prh[b]) * ah[b];

        const float x0 = cx - 0.5f * w, y0 = cy - 0.5f * h;
        const float x1 = cx + 0.5f * w, y1 = cy + 0.5f * h;

        float wi = fminf(x1, tx1) - fmaxf(x0, tx0);
        float hi = fminf(y1, ty1) - fmaxf(y0, ty0);
        wi = fmaxf(wi, 0.f);
        hi = fmaxf(hi, 0.f);
        const float inter = wi * hi;
        const float iou = inter * __builtin_amdgcn_rcpf(w * h + area_t - inter);

        // jnp.argmax keeps FIRST max -> strict '>'
        const bool better = iou > best_iou;
        best_iou = better ? iou : best_iou;
        best_b   = better ? b   : best_b;
        bcx  = better ? cx      : bcx;
        bcy  = better ? cy      : bcy;
        bw   = better ? w       : bw;
        bh   = better ? h       : bh;
        bobj = better ? pobj[b] : bobj;
    }

    // ---- data-dependent gather of the best box's 20 class scores ----
    const float* pb = pc + best_b * TSTR;
    float acc = 0.f;
    #pragma unroll
    for (int k = 0; k < C_; ++k) {
        float v = pb[k];
        if (k == 0) v *= (float)best_b;   // pbest[...,0] scaled by best_idx
        const float d = v - t[k];
        acc = fmaf(d, d, acc);
    }

    // xy SSE (transformed)
    float d;
    d = bcx - tcx; acc = fmaf(d, d, acc);
    d = bcy - tcy; acc = fmaf(d, d, acc);

    // wh SSE: sign(x)*sqrt(|x|+1e-6); bw,bh > 0 always
    d = sqrtf(bw + 1e-6f) - tw; acc = fmaf(d, d, acc);
    d = sqrtf(bh + 1e-6f) - th; acc = fmaf(d, d, acc);

    // obj / noobj share (pbest[20]-t[20])^2
    const float e    = t[C_];
    const float ne   = 1.f - e;
    const float dobj = bobj - e;
    float local = e * e * acc + (e * e + ne * ne) * (dobj * dobj);

    // wave(64) shuffle reduction, one atomic per wave into a striped bucket
    #pragma unroll
    for (int off = 32; off > 0; off >>= 1)
        local += __shfl_down(local, off, 64);

    if ((threadIdx.x & 63) == 0) {
        const int wid = (blockIdx.x << 2) | (threadIdx.x >> 6);
        atomicAdd(&buckets[(wid & (NBUCKET - 1)) * BUCKET_STRIDE], local);
    }
}

__global__ __launch_bounds__(64) void finalize_kernel(
    const float* __restrict__ buckets, float* __restrict__ out)
{
    float v = buckets[threadIdx.x * BUCKET_STRIDE];
    #pragma unroll
    for (int off = 32; off > 0; off >>= 1)
        v += __shfl_down(v, off, 64);
    if (threadIdx.x == 0) out[0] = v;
}

extern "C" void kernel_launch(void* const* d_in, const int* in_sizes, int n_in,
                              void* d_out, int out_size, void* d_ws, size_t ws_size,
                              hipStream_t stream) {
    const float* pred = (const float*)d_in[0];   // (N,S,S,B,C+5) f32
    const float* targ = (const float*)d_in[1];   // (N,S,S,C+5)   f32
    const float* anch = (const float*)d_in[2];   // (B,2)         f32
    float* out     = (float*)d_out;
    float* buckets = (float*)d_ws;               // 64 buckets, 128 B apart

    // d_ws is poisoned 0xAA before every timed launch — zero our buckets.
    hipMemsetAsync(buckets, 0, NBUCKET * BUCKET_STRIDE * sizeof(float), stream);

    yolo_loss_kernel<<<NBLK, TPB, 0, stream>>>(pred, targ, anch, buckets);
    finalize_kernel<<<1, 64, 0, stream>>>(buckets, out);
}

// Round 2
// 305.575 us; speedup vs baseline: 1.0480x; 1.0480x over previous
//
#include <hip/hip_runtime.h>

// Problem constants (from reference): S=56, B=5, C=20, N=128
constexpr int S_   = 56;
constexpr int B_   = 5;
constexpr int C_   = 20;
constexpr int N_   = 128;
constexpr int CELLS = N_ * S_ * S_;   // 401408
constexpr int PSTR  = B_ * (C_ + 5);  // 125 floats per cell (predicts)
constexpr int TSTR  = C_ + 5;         // 25 floats per cell (targets)

constexpr int CPB    = 64;            // cells per block (= 1 wave, 1 cell/thread)
constexpr int NBLK   = CELLS / CPB;   // 6272, exact
constexpr int PRED_B = CPB * PSTR * 4;  // 32000 bytes, contiguous in global
// LDS = 32000 B/block -> 5 blocks/CU (5 x 32 KiB = 160 KiB exactly).

// async global->LDS, 16 B per lane. LDS dest = wave-uniform base + lane*16.
__device__ __forceinline__ void gload_lds16(const char* g, char* l) {
    __builtin_amdgcn_global_load_lds(
        (const __attribute__((address_space(1))) void*)g,
        (__attribute__((address_space(3))) void*)l,
        16, 0, 0);
}

__global__ __launch_bounds__(64) void yolo_loss_kernel(
    const float* __restrict__ pred,
    const float* __restrict__ targ,
    const float* __restrict__ anch,   // [B,2]
    float* __restrict__ part)         // [NBLK] partials in d_ws
{
    __shared__ char lds[PRED_B];            // 32000 B -> 5 blocks/CU

    const int lane  = threadIdx.x;          // 0..63
    const int cell0 = blockIdx.x * CPB;
    const int cell  = cell0 + lane;

    // ---- coalesced streaming stage: pred -> LDS (1 KB per instruction) ----
    const char* gp = (const char*)(pred + (size_t)cell0 * PSTR);  // 32000 B
    #pragma unroll
    for (int it = 0; it < 31; ++it)                       // 31 * 1024 = 31744
        gload_lds16(gp + it * 1024 + lane * 16, lds + it * 1024);
    if (lane < 16)                                        // 256 B tail
        gload_lds16(gp + 31744 + lane * 16, lds + 31744);

    // ---- targets: 25 floats per thread, direct to VGPRs.
    // Wave footprint is a dense, contiguous 6.4 KB -> HBM-optimal; loads
    // overlap with the gload_lds DMA above.
    const float* __restrict__ tp = targ + (size_t)cell * TSTR;
    float t[TSTR];
    #pragma unroll
    for (int k = 0; k < TSTR; ++k) t[k] = tp[k];

    // anchors: 10 uniform floats, L1-resident broadcast
    float aw[B_], ah[B_];
    #pragma unroll
    for (int b = 0; b < B_; ++b) { aw[b] = anch[2 * b]; ah[b] = anch[2 * b + 1]; }

    // target-side prep (runs while pred DMA is in flight)
    const float tcx = t[C_ + 1], tcy = t[C_ + 2];
    const float tw  = t[C_ + 3], th  = t[C_ + 4];
    const float tx0 = tcx - 0.5f * tw, ty0 = tcy - 0.5f * th;
    const float tx1 = tcx + 0.5f * tw, ty1 = tcy + 0.5f * th;
    const float area_t = tw * th;

    __syncthreads();   // drains vmcnt(0) -> LDS valid

    // ---- compute: one cell per thread, pred operands in LDS ----
    const float* pc = (const float*)lds + (size_t)lane * PSTR;  // my 125 preds
    // LDS stride/lane = 125 dwords (odd) -> conflict-light banking.

    float best_iou = -1.f;
    int   best_b = 0;
    float bcx = 0.f, bcy = 0.f, bw = 0.f, bh = 0.f;

    #pragma unroll
    for (int b = 0; b < B_; ++b) {
        const float rcx = pc[b * TSTR + C_ + 1];
        const float rcy = pc[b * TSTR + C_ + 2];
        const float rw  = pc[b * TSTR + C_ + 3];
        const float rh  = pc[b * TSTR + C_ + 4];

        const float cx = __builtin_amdgcn_rcpf(1.f + __expf(-rcx)); // sigmoid
        const float cy = __builtin_amdgcn_rcpf(1.f + __expf(-rcy));
        const float w  = __expf(rw) * aw[b];
        const float h  = __expf(rh) * ah[b];

        const float x0 = cx - 0.5f * w, y0 = cy - 0.5f * h;
        const float x1 = cx + 0.5f * w, y1 = cy + 0.5f * h;

        float wi = fminf(x1, tx1) - fmaxf(x0, tx0);
        float hi = fminf(y1, ty1) - fmaxf(y0, ty0);
        wi = fmaxf(wi, 0.f);
        hi = fmaxf(hi, 0.f);
        const float inter = wi * hi;
        const float iou = inter * __builtin_amdgcn_rcpf(w * h + area_t - inter);

        // jnp.argmax keeps FIRST max -> strict '>'
        const bool better = iou > best_iou;
        best_iou = better ? iou : best_iou;
        best_b   = better ? b   : best_b;
        bcx = better ? cx : bcx;
        bcy = better ? cy : bcy;
        bw  = better ? w  : bw;
        bh  = better ? h  : bh;
    }

    const float* pb = pc + best_b * TSTR;   // divergent LDS offset — fine

    // class SSE (pbest[...,0] scaled by best_idx per reference)
    float acc = 0.f;
    #pragma unroll
    for (int k = 0; k < C_; ++k) {
        float v = pb[k];
        if (k == 0) v *= (float)best_b;
        const float d = v - t[k];
        acc = fmaf(d, d, acc);
    }

    // xy SSE (transformed)
    float d;
    d = bcx - tcx; acc = fmaf(d, d, acc);
    d = bcy - tcy; acc = fmaf(d, d, acc);

    // wh SSE: sign(x)*sqrt(|x|+1e-6); bw,bh > 0 always
    d = sqrtf(bw + 1e-6f) - tw; acc = fmaf(d, d, acc);
    d = sqrtf(bh + 1e-6f) - th; acc = fmaf(d, d, acc);

    // obj / noobj share (pbest[20]-t[20])^2
    const float e    = t[C_];
    const float ne   = 1.f - e;
    const float dobj = pb[C_] - e;
    float local = e * e * acc + (e * e + ne * ne) * (dobj * dobj);

    // wave(64) shuffle reduction, then ONE plain store per block.
    // Overwrite semantics -> poison-safe, no memset dispatch, no atomics.
    #pragma unroll
    for (int off = 32; off > 0; off >>= 1)
        local += __shfl_down(local, off, 64);

    if (lane == 0)
        part[blockIdx.x] = local;
}

__global__ __launch_bounds__(1024) void finalize_kernel(
    const float* __restrict__ part, float* __restrict__ out)
{
    float v = 0.f;
    for (int i = threadIdx.x; i < NBLK; i += 1024)   // 6272 floats, coalesced
        v += part[i];

    #pragma unroll
    for (int off = 32; off > 0; off >>= 1)
        v += __shfl_down(v, off, 64);

    __shared__ float ws[16];
    if ((threadIdx.x & 63) == 0) ws[threadIdx.x >> 6] = v;
    __syncthreads();
    if (threadIdx.x < 16) {
        float x = ws[threadIdx.x];
        #pragma unroll
        for (int off = 8; off > 0; off >>= 1)
            x += __shfl_down(x, off, 16);
        if (threadIdx.x == 0) out[0] = x;
    }
}

extern "C" void kernel_launch(void* const* d_in, const int* in_sizes, int n_in,
                              void* d_out, int out_size, void* d_ws, size_t ws_size,
                              hipStream_t stream) {
    const float* pred = (const float*)d_in[0];   // (N,S,S,B,C+5) f32
    const float* targ = (const float*)d_in[1];   // (N,S,S,C+5)   f32
    const float* anch = (const float*)d_in[2];   // (B,2)         f32
    float* out  = (float*)d_out;
    float* part = (float*)d_ws;                  // NBLK partials (overwritten)

    yolo_loss_kernel<<<NBLK, CPB, 0, stream>>>(pred, targ, anch, part);
    finalize_kernel<<<1, 1024, 0, stream>>>(part, out);
}

// Round 3
// 304.771 us; speedup vs baseline: 1.0507x; 1.0026x over previous
//
#include <hip/hip_runtime.h>

// Problem constants (from reference): S=56, B=5, C=20, N=128
constexpr int S_   = 56;
constexpr int B_   = 5;
constexpr int C_   = 20;
constexpr int N_   = 128;
constexpr int CELLS = N_ * S_ * S_;   // 401408
constexpr int PSTR  = B_ * (C_ + 5);  // 125 floats per cell (predicts)
constexpr int TSTR  = C_ + 5;         // 25 floats per cell (targets)

constexpr int GC    = 64;                 // cells per group (= 1 wave, 1 cell/lane)
constexpr int GPB   = 4;                  // groups per block (pipelined)
constexpr int NBLK  = CELLS / (GC * GPB); // 1568, exact
constexpr int GP_B  = GC * PSTR * 4;      // 32000 B pred per group
constexpr int GT_B  = GC * TSTR * 4;      // 6400 B targ per group
constexpr int GRP_B = GP_B + GT_B;        // 38400 B per group buffer
// LDS: 2 buffers = 76800 B -> 2 blocks/CU; each wave keeps 39-78 VMEM ops
// (38-77 KB) in flight at all times via counted vmcnt (no barrier: 1-wave
// blocks own their LDS, so s_waitcnt alone is the full sync).

// async global->LDS, 16 B per lane. LDS dest = wave-uniform base + lane*16.
__device__ __forceinline__ void gload_lds16(const char* g, char* l) {
    __builtin_amdgcn_global_load_lds(
        (const __attribute__((address_space(1))) void*)g,
        (__attribute__((address_space(3))) void*)l,
        16, 0, 0);
}

#define WAITVM(N) asm volatile("s_waitcnt vmcnt(" #N ")" ::: "memory")

// Issue one group's staging: 31+1 pred ops + 6+1 targ ops = 39 VMEM ops.
__device__ __forceinline__ void stage_group(const float* __restrict__ pred,
                                            const float* __restrict__ targ,
                                            int g, char* buf, int lane) {
    const char* gp = (const char*)(pred + (size_t)g * GC * PSTR);  // 32000 B
    const char* gt = (const char*)(targ + (size_t)g * GC * TSTR);  //  6400 B
    #pragma unroll
    for (int it = 0; it < 31; ++it)                      // 31 * 1024 = 31744
        gload_lds16(gp + it * 1024 + lane * 16, buf + it * 1024);
    if (lane < 16)                                       // 256 B tail
        gload_lds16(gp + 31744 + lane * 16, buf + 31744);
    #pragma unroll
    for (int it = 0; it < 6; ++it)                       // 6 * 1024 = 6144
        gload_lds16(gt + it * 1024 + lane * 16, buf + GP_B + it * 1024);
    if (lane < 16)                                       // 256 B tail
        gload_lds16(gt + 6144 + lane * 16, buf + GP_B + 6144);
}

// Per-cell loss from a staged group buffer (lane = cell within group).
__device__ __forceinline__ float cell_loss(const char* buf, int lane,
                                           const float* aw, const float* ah) {
    const float* pc = (const float*)buf + (size_t)lane * PSTR;           // 125 preds
    const float* tp = (const float*)(buf + GP_B) + (size_t)lane * TSTR;  // 25 targs
    // LDS stride/lane: 125 and 25 dwords (odd) -> conflict-light banking.

    const float tcx = tp[C_ + 1], tcy = tp[C_ + 2];
    const float tw  = tp[C_ + 3], th  = tp[C_ + 4];
    const float tx0 = tcx - 0.5f * tw, ty0 = tcy - 0.5f * th;
    const float tx1 = tcx + 0.5f * tw, ty1 = tcy + 0.5f * th;
    const float area_t = tw * th;

    float best_iou = -1.f;
    int   best_b = 0;
    float bcx = 0.f, bcy = 0.f, bw = 0.f, bh = 0.f;

    #pragma unroll
    for (int b = 0; b < B_; ++b) {
        const float rcx = pc[b * TSTR + C_ + 1];
        const float rcy = pc[b * TSTR + C_ + 2];
        const float rw  = pc[b * TSTR + C_ + 3];
        const float rh  = pc[b * TSTR + C_ + 4];

        const float cx = __builtin_amdgcn_rcpf(1.f + __expf(-rcx)); // sigmoid
        const float cy = __builtin_amdgcn_rcpf(1.f + __expf(-rcy));
        const float w  = __expf(rw) * aw[b];
        const float h  = __expf(rh) * ah[b];

        const float x0 = cx - 0.5f * w, y0 = cy - 0.5f * h;
        const float x1 = cx + 0.5f * w, y1 = cy + 0.5f * h;

        float wi = fminf(x1, tx1) - fmaxf(x0, tx0);
        float hi = fminf(y1, ty1) - fmaxf(y0, ty0);
        wi = fmaxf(wi, 0.f);
        hi = fmaxf(hi, 0.f);
        const float inter = wi * hi;
        const float iou = inter * __builtin_amdgcn_rcpf(w * h + area_t - inter);

        // jnp.argmax keeps FIRST max -> strict '>'
        const bool better = iou > best_iou;
        best_iou = better ? iou : best_iou;
        best_b   = better ? b   : best_b;
        bcx = better ? cx : bcx;
        bcy = better ? cy : bcy;
        bw  = better ? w  : bw;
        bh  = better ? h  : bh;
    }

    const float* pb = pc + best_b * TSTR;   // divergent LDS offset — fine

    // class SSE (pbest[...,0] scaled by best_idx per reference)
    float acc = 0.f;
    #pragma unroll
    for (int k = 0; k < C_; ++k) {
        float v = pb[k];
        if (k == 0) v *= (float)best_b;
        const float d = v - tp[k];
        acc = fmaf(d, d, acc);
    }

    // xy SSE (transformed)
    float d;
    d = bcx - tcx; acc = fmaf(d, d, acc);
    d = bcy - tcy; acc = fmaf(d, d, acc);

    // wh SSE: sign(x)*sqrt(|x|+1e-6); bw,bh > 0 always
    d = sqrtf(bw + 1e-6f) - tw; acc = fmaf(d, d, acc);
    d = sqrtf(bh + 1e-6f) - th; acc = fmaf(d, d, acc);

    // obj / noobj share (pbest[20]-t[20])^2
    const float e    = tp[C_];
    const float ne   = 1.f - e;
    const float dobj = pb[C_] - e;
    return e * e * acc + (e * e + ne * ne) * (dobj * dobj);
}

__global__ __launch_bounds__(64) void yolo_loss_kernel(
    const float* __restrict__ pred,
    const float* __restrict__ targ,
    const float* __restrict__ anch,   // [B,2]
    float* __restrict__ part)         // [NBLK] partials in d_ws
{
    __shared__ char lds[2 * GRP_B];   // 76800 B -> 2 blocks/CU

    const int lane = threadIdx.x;     // 0..63
    const int g0   = blockIdx.x * GPB;

    // anchors: 10 uniform floats, L1-resident broadcast
    float aw[B_], ah[B_];
    #pragma unroll
    for (int b = 0; b < B_; ++b) { aw[b] = anch[2 * b]; ah[b] = anch[2 * b + 1]; }

    // ---- 2-deep counted-vmcnt pipeline: 39 DMA ops per group stay in
    // flight across every compute phase; vmcnt never drains to 0 until
    // the final group. No __syncthreads anywhere (1 wave owns the LDS).
    stage_group(pred, targ, g0 + 0, lds,         lane);   // 39 ops
    stage_group(pred, targ, g0 + 1, lds + GRP_B, lane);   // 39 ops (78 out)

    float total = 0.f;

    WAITVM(39);                                  // group 0 landed, 1 in flight
    total += cell_loss(lds,         lane, aw, ah);
    stage_group(pred, targ, g0 + 2, lds,         lane);

    WAITVM(39);                                  // group 1 landed, 2 in flight
    total += cell_loss(lds + GRP_B, lane, aw, ah);
    stage_group(pred, targ, g0 + 3, lds + GRP_B, lane);

    WAITVM(39);                                  // group 2 landed, 3 in flight
    total += cell_loss(lds,         lane, aw, ah);

    WAITVM(0);                                   // group 3 landed
    total += cell_loss(lds + GRP_B, lane, aw, ah);

    // wave(64) shuffle reduction, then ONE plain store per block.
    // Overwrite semantics -> poison-safe, no memset dispatch, no atomics.
    #pragma unroll
    for (int off = 32; off > 0; off >>= 1)
        total += __shfl_down(total, off, 64);

    if (lane == 0)
        part[blockIdx.x] = total;
}

__global__ __launch_bounds__(1024) void finalize_kernel(
    const float* __restrict__ part, float* __restrict__ out)
{
    float v = 0.f;
    for (int i = threadIdx.x; i < NBLK; i += 1024)   // 1568 floats, coalesced
        v += part[i];

    #pragma unroll
    for (int off = 32; off > 0; off >>= 1)
        v += __shfl_down(v, off, 64);

    __shared__ float ws[16];
    if ((threadIdx.x & 63) == 0) ws[threadIdx.x >> 6] = v;
    __syncthreads();
    if (threadIdx.x < 16) {
        float x = ws[threadIdx.x];
        #pragma unroll
        for (int off = 8; off > 0; off >>= 1)
            x += __shfl_down(x, off, 16);
        if (threadIdx.x == 0) out[0] = x;
    }
}

extern "C" void kernel_launch(void* const* d_in, const int* in_sizes, int n_in,
                              void* d_out, int out_size, void* d_ws, size_t ws_size,
                              hipStream_t stream) {
    const float* pred = (const float*)d_in[0];   // (N,S,S,B,C+5) f32
    const float* targ = (const float*)d_in[1];   // (N,S,S,C+5)   f32
    const float* anch = (const float*)d_in[2];   // (B,2)         f32
    float* out  = (float*)d_out;
    float* part = (float*)d_ws;                  // NBLK partials (overwritten)

    yolo_loss_kernel<<<NBLK, 64, 0, stream>>>(pred, targ, anch, part);
    finalize_kernel<<<1, 1024, 0, stream>>>(part, out);
}

// Round 4
// 302.742 us; speedup vs baseline: 1.0578x; 1.0067x over previous
//
#include <hip/hip_runtime.h>

// Problem constants (from reference): S=56, B=5, C=20, N=128
constexpr int S_   = 56;
constexpr int B_   = 5;
constexpr int C_   = 20;
constexpr int N_   = 128;
constexpr int CELLS = N_ * S_ * S_;   // 401408
constexpr int PSTR  = B_ * (C_ + 5);  // 125 floats per cell (predicts)
constexpr int TSTR  = C_ + 5;         // 25 floats per cell (targets)

constexpr int CPB    = 32;            // cells per block (1-wave block, half-wave compute)
constexpr int NBLK   = CELLS / CPB;   // 12544, exact
constexpr int PRED_B = CPB * PSTR * 4;  // 16000 B, contiguous in global
constexpr int TARG_B = CPB * TSTR * 4;  //  3200 B, contiguous in global
// LDS = 19200 B/block -> 8 blocks/CU (163840/19200 = 8.5). 8 independent
// DMA streams per CU; sync-drain blocks (R0 structure, measured best) —
// inter-block overlap does the pipelining, not per-wave vmcnt counting.

// async global->LDS, 16 B per lane. LDS dest = wave-uniform base + lane*16.
__device__ __forceinline__ void gload_lds16(const char* g, char* l) {
    __builtin_amdgcn_global_load_lds(
        (const __attribute__((address_space(1))) void*)g,
        (__attribute__((address_space(3))) void*)l,
        16, 0, 0);
}

#define WAITVM0() asm volatile("s_waitcnt vmcnt(0)" ::: "memory")

__global__ __launch_bounds__(64) void yolo_loss_kernel(
    const float* __restrict__ pred,
    const float* __restrict__ targ,
    const float* __restrict__ anch,   // [B,2]
    float* __restrict__ part)         // [NBLK] partials in d_ws
{
    __shared__ char lds[PRED_B + TARG_B];   // 19200 B

    const int lane  = threadIdx.x;          // 0..63
    const int cell0 = blockIdx.x * CPB;

    // ---- coalesced streaming stage: global -> LDS (1 KB per instruction) ----
    const char* gp = (const char*)(pred + (size_t)cell0 * PSTR);  // 16000 B
    const char* gt = (const char*)(targ + (size_t)cell0 * TSTR);  //  3200 B

    #pragma unroll
    for (int it = 0; it < 15; ++it)                       // 15 * 1024 = 15360
        gload_lds16(gp + it * 1024 + lane * 16, lds + it * 1024);
    #pragma unroll
    for (int it = 0; it < 3; ++it)                        // 3 * 1024 = 3072
        gload_lds16(gt + it * 1024 + lane * 16, lds + PRED_B + it * 1024);
    if (lane < 40)                                        // 640 B pred tail
        gload_lds16(gp + 15360 + lane * 16, lds + 15360);
    if (lane < 8)                                         // 128 B targ tail
        gload_lds16(gt + 3072 + lane * 16, lds + PRED_B + 3072);

    // anchors: 10 uniform floats, L1-resident broadcast (overlaps DMA)
    float aw[B_], ah[B_];
    #pragma unroll
    for (int b = 0; b < B_; ++b) { aw[b] = anch[2 * b]; ah[b] = anch[2 * b + 1]; }

    WAITVM0();   // single-wave block: vmcnt(0) alone makes LDS valid

    float local = 0.f;
    if (lane < CPB) {
        // ---- compute: one cell per active lane, all operands in LDS ----
        const float* pc = (const float*)lds + (size_t)lane * PSTR;            // 125 preds
        const float* tp = (const float*)(lds + PRED_B) + (size_t)lane * TSTR; // 25 targets

        const float tcx = tp[C_ + 1], tcy = tp[C_ + 2];
        const float tw  = tp[C_ + 3], th  = tp[C_ + 4];
        const float tx0 = tcx - 0.5f * tw, ty0 = tcy - 0.5f * th;
        const float tx1 = tcx + 0.5f * tw, ty1 = tcy + 0.5f * th;
        const float area_t = tw * th;

        float best_iou = -1.f;
        int   best_b = 0;
        float bcx = 0.f, bcy = 0.f, bw = 0.f, bh = 0.f;

        #pragma unroll
        for (int b = 0; b < B_; ++b) {
            const float rcx = pc[b * TSTR + C_ + 1];
            const float rcy = pc[b * TSTR + C_ + 2];
            const float rw  = pc[b * TSTR + C_ + 3];
            const float rh  = pc[b * TSTR + C_ + 4];

            const float cx = __builtin_amdgcn_rcpf(1.f + __expf(-rcx)); // sigmoid
            const float cy = __builtin_amdgcn_rcpf(1.f + __expf(-rcy));
            const float w  = __expf(rw) * aw[b];
            const float h  = __expf(rh) * ah[b];

            const float x0 = cx - 0.5f * w, y0 = cy - 0.5f * h;
            const float x1 = cx + 0.5f * w, y1 = cy + 0.5f * h;

            float wi = fminf(x1, tx1) - fmaxf(x0, tx0);
            float hi = fminf(y1, ty1) - fmaxf(y0, ty0);
            wi = fmaxf(wi, 0.f);
            hi = fmaxf(hi, 0.f);
            const float inter = wi * hi;
            const float iou = inter * __builtin_amdgcn_rcpf(w * h + area_t - inter);

            // jnp.argmax keeps FIRST max -> strict '>'
            const bool better = iou > best_iou;
            best_iou = better ? iou : best_iou;
            best_b   = better ? b   : best_b;
            bcx = better ? cx : bcx;
            bcy = better ? cy : bcy;
            bw  = better ? w  : bw;
            bh  = better ? h  : bh;
        }

        const float* pb = pc + best_b * TSTR;   // divergent LDS offset — fine

        // class SSE (pbest[...,0] scaled by best_idx per reference)
        float acc = 0.f;
        #pragma unroll
        for (int k = 0; k < C_; ++k) {
            float v = pb[k];
            if (k == 0) v *= (float)best_b;
            const float d = v - tp[k];
            acc = fmaf(d, d, acc);
        }

        // xy SSE (transformed)
        float d;
        d = bcx - tcx; acc = fmaf(d, d, acc);
        d = bcy - tcy; acc = fmaf(d, d, acc);

        // wh SSE: sign(x)*sqrt(|x|+1e-6); bw,bh > 0 always
        d = sqrtf(bw + 1e-6f) - tw; acc = fmaf(d, d, acc);
        d = sqrtf(bh + 1e-6f) - th; acc = fmaf(d, d, acc);

        // obj / noobj share (pbest[20]-t[20])^2
        const float e    = tp[C_];
        const float ne   = 1.f - e;
        const float dobj = pb[C_] - e;
        local = e * e * acc + (e * e + ne * ne) * (dobj * dobj);
    }

    // width-32 shuffle reduction (lanes 0..31 hold values), one plain store.
    // Overwrite semantics -> poison-safe, no memset, no atomics.
    #pragma unroll
    for (int off = 16; off > 0; off >>= 1)
        local += __shfl_down(local, off, 32);

    if (lane == 0)
        part[blockIdx.x] = local;
}

__global__ __launch_bounds__(1024) void finalize_kernel(
    const float* __restrict__ part, float* __restrict__ out)
{
    float v = 0.f;
    for (int i = threadIdx.x; i < NBLK; i += 1024)   // 12544 floats, coalesced
        v += part[i];

    #pragma unroll
    for (int off = 32; off > 0; off >>= 1)
        v += __shfl_down(v, off, 64);

    __shared__ float ws[16];
    if ((threadIdx.x & 63) == 0) ws[threadIdx.x >> 6] = v;
    __syncthreads();
    if (threadIdx.x < 16) {
        float x = ws[threadIdx.x];
        #pragma unroll
        for (int off = 8; off > 0; off >>= 1)
            x += __shfl_down(x, off, 16);
        if (threadIdx.x == 0) out[0] = x;
    }
}

extern "C" void kernel_launch(void* const* d_in, const int* in_sizes, int n_in,
                              void* d_out, int out_size, void* d_ws, size_t ws_size,
                              hipStream_t stream) {
    const float* pred = (const float*)d_in[0];   // (N,S,S,B,C+5) f32
    const float* targ = (const float*)d_in[1];   // (N,S,S,C+5)   f32
    const float* anch = (const float*)d_in[2];   // (B,2)         f32
    float* out  = (float*)d_out;
    float* part = (float*)d_ws;                  // NBLK partials (overwritten)

    yolo_loss_kernel<<<NBLK, 64, 0, stream>>>(pred, targ, anch, part);
    finalize_kernel<<<1, 1024, 0, stream>>>(part, out);
}